// Round 9
// baseline (3365.741 us; speedup 1.0000x reference)
//
#include <hip/hip_runtime.h>
#include <stdint.h>

#define TT 2560
#define BB 64
#define CC 22

typedef unsigned short ushort_t;
typedef __attribute__((ext_vector_type(4))) float floatx4;
typedef __attribute__((ext_vector_type(8))) short bf16x8;

__device__ __forceinline__ float bf2f(ushort_t u){
  union { uint32_t i; float f; } v; v.i = ((uint32_t)u) << 16; return v.f;
}
__device__ __forceinline__ ushort_t f2bf(float f){
  union { float f; uint32_t i; } v; v.f = f;
  uint32_t r = v.i + 0x7FFFu + ((v.i >> 16) & 1u);
  return (ushort_t)(r >> 16);
}
__device__ __forceinline__ float fsig(float x){ return 1.f/(1.f + __expf(-x)); }
__device__ __forceinline__ float ftanh(float x){ return 2.f/(1.f + __expf(-2.f*x)) - 1.f; }

// LDS-only barrier: does NOT drain vmcnt; global stores/prefetch loads stay in
// flight across the 2560-step serial loop.
__device__ __forceinline__ void ldsbar(){
  asm volatile("s_waitcnt lgkmcnt(0)\n\ts_barrier" ::: "memory");
}

// ---------------- K0a: cast x [B][C][T] fp32 -> xc [B][C][T] bf16 (time-contiguous)
__global__ __launch_bounds__(256) void k_convert_x(const float* __restrict__ x, ushort_t* __restrict__ xc){
  int i4 = blockIdx.x*256 + threadIdx.x;
  if (i4 >= BB*CC*TT/4) return;
  const float4 v = ((const float4*)x)[i4];
  uint2 o;
  o.x = (uint32_t)f2bf(v.x) | ((uint32_t)f2bf(v.y) << 16);
  o.y = (uint32_t)f2bf(v.z) | ((uint32_t)f2bf(v.w) << 16);
  ((uint2*)xc)[i4] = o;
}

// ---------------- K0a2: pack x into MFMA A-fragment order.
// xA[cb][t][l16] (16B each): l16 = c4*4+q -> lane (m=c4*4, q); elems j: channel c=q*8+j
// value = xc[b=cb*4+c4][c][t] (c<22) else 0. Same fragment serves fwd and bwd.
__global__ __launch_bounds__(256) void k_prep_xa(const ushort_t* __restrict__ xc, ushort_t* __restrict__ xA){
  int idx = blockIdx.x*256 + threadIdx.x;          // (cb*TT + t)*16 + l16
  if (idx >= 16*TT*16) return;
  int l16 = idx & 15;
  int rest = idx >> 4;
  int t = rest % TT, cb = rest / TT;
  int c4 = l16 >> 2, q = l16 & 3;
  int b = cb*4 + c4;
  ushort_t v[8];
  #pragma unroll
  for (int j=0;j<8;j++){
    int c = q*8 + j;
    v[j] = (c < CC) ? xc[((size_t)b*CC + c)*TT + t] : (ushort_t)0;
  }
  *(uint4*)(xA + (size_t)idx*8) = *(const uint4*)v;
}

// ---------------- K0b: B0T[dir][n=512][k=160]: k<128 Wh0[k][n]; 128..149 Wx0[k-128][n]; else 0
__global__ __launch_bounds__(256) void k_prep_l0(const float* __restrict__ WxF, const float* __restrict__ WhF,
                                                 const float* __restrict__ WxB, const float* __restrict__ WhB,
                                                 ushort_t* __restrict__ B0T){
  int idx = blockIdx.x*256 + threadIdx.x;
  if (idx >= 2*512*160) return;
  int dir = idx / 81920; int r = idx % 81920; int n = r / 160; int k = r % 160;
  const float* Wh = dir ? WhB : WhF;
  const float* Wx = dir ? WxB : WxF;
  float v = (k < 128) ? Wh[k*512 + n] : (((k-128) < CC) ? Wx[(k-128)*512 + n] : 0.f);
  B0T[idx] = f2bf(v);
}

// ---------------- K0c: B1T[dir][n=256][k=64] = Wh1[k][n]
__global__ __launch_bounds__(256) void k_prep_l1(const float* __restrict__ WhF, const float* __restrict__ WhB,
                                                 ushort_t* __restrict__ B1T){
  int idx = blockIdx.x*256 + threadIdx.x;
  if (idx >= 2*256*64) return;
  int dir = idx >> 14; int r = idx & 16383; int n = r >> 6; int k = r & 63;
  const float* Wh = dir ? WhB : WhF;
  B1T[idx] = f2bf(Wh[k*256 + n]);
}

// ---------------- K0d: WT[dir][n=256][k=256] = Wx1[k][n]  (for xz1 gemm)
__global__ __launch_bounds__(256) void k_prep_wxT(const float* __restrict__ Wf, const float* __restrict__ Wb,
                                                  ushort_t* __restrict__ WT){
  int idx = blockIdx.x*256 + threadIdx.x;
  int dir = idx >> 16; int r = idx & 65535; int n = r >> 8; int k = r & 255;
  const float* W = dir ? Wb : Wf;
  WT[idx] = f2bf(W[k*256 + n]);
}

// ---------------- K1: layer-0 MFMA scan. 4 chains/WG, 8 waves (2/SIMD), 32 WGs.
// h k-tiles (0..3) from LDS; x k-tile (4) from per-lane global-prefetched registers.
__global__ __launch_bounds__(512, 2) void k_lstm0m(
  const ushort_t* __restrict__ xA, const ushort_t* __restrict__ B0T,
  const float* __restrict__ bF, const float* __restrict__ bB,
  ushort_t* __restrict__ h0seq)                     // [B][T][256]: fwd 0..127, bwd 128..255
{
  const int dir = blockIdx.x & 1, cb = blockIdx.x >> 1;   // cb 0..15
  const int tid = threadIdx.x;
  const int wv = tid >> 6, lane = tid & 63, m = lane & 15, q = lane >> 4;
  const int u = wv*16 + m;                                // unit 0..127
  const float* bi = dir ? bB : bF;

  __shared__ __align__(16) ushort_t Abuf[2][16][136];  // rows 4q: h 0..127 | 8 pad

  bf16x8 Bf[4][5];                                     // [gate][ktile] register-resident
  const ushort_t* Bb = B0T + (size_t)dir*512*160;
  #pragma unroll
  for (int g=0; g<4; g++){
    int nt = g*8 + wv;
    #pragma unroll
    for (int kt=0; kt<5; kt++)
      Bf[g][kt] = *(const bf16x8*)(Bb + (size_t)(nt*16+m)*160 + kt*32 + q*8);
  }
  float bz[4];
  #pragma unroll
  for (int g=0; g<4; g++) bz[g] = bi[g*128 + u];

  for (int i = tid; i < (int)(sizeof(Abuf)/4); i += 512) ((uint32_t*)Abuf)[i] = 0u;

  // x fragment stream: only lanes m%4==0 carry nonzero A rows (row m = chain m/4)
  const bool xact = ((m & 3) == 0);
  const ushort_t* xap = xA + (((size_t)cb*TT)*16 + (size_t)((m>>2)*4 + q))*8;
  uint4 px[4];
  #pragma unroll
  for (int j=0; j<4; j++){
    int tj = dir ? (TT-1-j) : j;
    if (xact) px[j] = *(const uint4*)(xap + (size_t)tj*128);
  }
  __syncthreads();

  const floatx4 z4 = {0.f,0.f,0.f,0.f};   // persistent zero C-operand
  float cst = 0.f;
  const int t00 = dir ? TT-1 : 0;
  ushort_t* hp = h0seq + ((size_t)(cb*4 + q)*TT + t00)*256 + dir*128 + u;
  const int hstep = dir ? -256 : 256;

  for (int i = 0; i < TT/4; ++i){
    #pragma unroll
    for (int p = 0; p < 4; ++p){
      const int s = i*4 + p;
      const int cur = s & 1, nxt = cur ^ 1;

      bf16x8 Af[4];
      const ushort_t* ar = &Abuf[cur][m][0];
      #pragma unroll
      for (int kt=0; kt<4; kt++) Af[kt] = *(const bf16x8*)(ar + kt*32 + q*8);
      bf16x8 Ax = (bf16x8)(short)0;
      if (xact) Ax = *(const bf16x8*)&px[p];

      floatx4 a[4];
      #pragma unroll
      for (int g=0; g<4; g++)
        a[g] = __builtin_amdgcn_mfma_f32_16x16x32_bf16(Af[0], Bf[g][0], z4, 0,0,0);
      #pragma unroll
      for (int kt=1; kt<4; kt++)
        #pragma unroll
        for (int g=0; g<4; g++)
          a[g] = __builtin_amdgcn_mfma_f32_16x16x32_bf16(Af[kt], Bf[g][kt], a[g], 0,0,0);
      #pragma unroll
      for (int g=0; g<4; g++)
        a[g] = __builtin_amdgcn_mfma_f32_16x16x32_bf16(Ax, Bf[g][4], a[g], 0,0,0);

      // reload px[p] for step s+4 (consumed-then-reload: wait lands 4 steps later)
      if (xact){
        int sn = s + 4; if (sn > TT-1) sn = TT-1;
        int tn = dir ? (TT-1-sn) : sn;
        px[p] = *(const uint4*)(xap + (size_t)tn*128);
      }

      {  // one gate-set per lane: unit u, chain q
        float ig = fsig (a[0][0] + bz[0]);
        float fg = fsig (a[1][0] + bz[1]);
        float gg = ftanh(a[2][0] + bz[2]);
        float og = fsig (a[3][0] + bz[3]);
        float cc = fg*cst + ig*gg;
        cst = cc;
        ushort_t hv = f2bf(og*ftanh(cc));
        Abuf[nxt][q*4][u] = hv;
        *hp = hv; hp += hstep;              // fire-and-forget
      }
      ldsbar();
    }
  }
}

// ---------------- K2: xz1R[dir][b][t][u(64)][g(4)] = bf16( h0seq[bt][:256] @ Wx1[dir] )
__global__ __launch_bounds__(512) void k_xz1_gemm(const ushort_t* __restrict__ h0seq,
                                                  const ushort_t* __restrict__ WxT,
                                                  ushort_t* __restrict__ xz1)
{
  const int mb  = blockIdx.x;
  const int dir = blockIdx.y;
  const ushort_t* W   = WxT + (size_t)dir*256*256;
  ushort_t*       out = xz1 + (size_t)dir*BB*TT*256;
  const int wave = threadIdx.x >> 6;
  const int lane = threadIdx.x & 63;
  const int mw = wave & 3;
  const int nw = wave >> 2;       // n-half: gates {2nw, 2nw+1}
  const int m_ = lane & 15;
  const int q_ = lane >> 4;

  floatx4 acc[2][8];
  #pragma unroll
  for (int a=0;a<2;a++)
    #pragma unroll
    for (int n=0;n<8;n++) acc[a][n] = (floatx4)0.f;

  const size_t Abase = ((size_t)mb*128 + mw*32 + m_)*256 + q_*8;
  const size_t Bbase = ((size_t)nw*128 + m_)*256 + q_*8;

  for (int kc = 0; kc < 256; kc += 32){
    bf16x8 afr[2];
    #pragma unroll
    for (int mt=0;mt<2;mt++)
      afr[mt] = *(const bf16x8*)(h0seq + Abase + (size_t)mt*16*256 + kc);
    #pragma unroll
    for (int nt=0;nt<8;nt++){
      bf16x8 bfr = *(const bf16x8*)(W + Bbase + (size_t)nt*16*256 + kc);
      #pragma unroll
      for (int mt=0;mt<2;mt++)
        acc[mt][nt] = __builtin_amdgcn_mfma_f32_16x16x32_bf16(afr[mt], bfr, acc[mt][nt], 0,0,0);
    }
  }
  #pragma unroll
  for (int mt=0;mt<2;mt++)
    #pragma unroll
    for (int r=0;r<4;r++){
      size_t bt = (size_t)mb*128 + mw*32 + mt*16 + q_*4 + r;
      ushort_t* rowp = out + bt*256;
      #pragma unroll
      for (int wvz=0; wvz<4; wvz++){
        uint32_t lo = f2bf(acc[mt][wvz][r]);
        uint32_t hi = f2bf(acc[mt][wvz+4][r]);
        *(uint32_t*)(rowp + (wvz*16+m_)*4 + 2*nw) = lo | (hi << 16);
      }
    }
}

// ---------------- K3: layer-1 MFMA scan. 4 chains/WG, 4 waves, 32 WGs. Unrolled x4;
// per-lane xz stream prefetched 4 steps ahead.
__global__ __launch_bounds__(256, 1) void k_lstm1m(
  const ushort_t* __restrict__ xz1R,                // [dir][b][t][u][g] bf16
  const ushort_t* __restrict__ B1T,                 // [dir][n=256][k=64] bf16
  const float* __restrict__ bF, const float* __restrict__ bB,
  float* __restrict__ h1last)                       // [B][128]: fwd 0..63, bwd 64..127
{
  const int dir = blockIdx.x & 1, cb = blockIdx.x >> 1;   // cb 0..15
  const int tid = threadIdx.x;
  const int wv = tid >> 6, lane = tid & 63, m = lane & 15, q = lane >> 4;
  const int u = wv*16 + m;                                // unit 0..63
  const float* bi = dir ? bB : bF;

  __shared__ __align__(16) ushort_t Hbuf[2][16][88];

  bf16x8 Bf[4][2];                        // gate g -> n-tile g*4+wv
  const ushort_t* Bb = B1T + (size_t)dir*256*64;
  #pragma unroll
  for (int g=0; g<4; g++){
    int nt = g*4 + wv;
    #pragma unroll
    for (int kt=0; kt<2; kt++)
      Bf[g][kt] = *(const bf16x8*)(Bb + (size_t)(nt*16+m)*64 + kt*32 + q*8);
  }
  float bz[4];
  #pragma unroll
  for (int g=0; g<4; g++) bz[g] = bi[g*64 + u];

  for (int i = tid; i < (int)(sizeof(Hbuf)/4); i += 256) ((uint32_t*)Hbuf)[i] = 0u;

  const ushort_t* xzr = xz1R + ((size_t)dir*BB + (size_t)(cb*4+q))*TT*256 + (size_t)u*4;
  uint2 pz[4];
  #pragma unroll
  for (int j=0; j<4; j++){
    int tj = dir ? (TT-1-j) : j;
    pz[j] = *(const uint2*)(xzr + (size_t)tj*256);
  }
  __syncthreads();

  const floatx4 z4 = {0.f,0.f,0.f,0.f};
  float cst = 0.f, hl = 0.f;

  for (int i = 0; i < TT/4; ++i){
    #pragma unroll
    for (int p = 0; p < 4; ++p){
      const int s = i*4 + p;
      const int cur = s & 1, nxt = cur ^ 1;

      bf16x8 Af[2];
      const ushort_t* ar = &Hbuf[cur][m][0];
      Af[0] = *(const bf16x8*)(ar + q*8);
      Af[1] = *(const bf16x8*)(ar + 32 + q*8);

      floatx4 a0 = __builtin_amdgcn_mfma_f32_16x16x32_bf16(Af[0], Bf[0][0], z4, 0,0,0);
      floatx4 a1 = __builtin_amdgcn_mfma_f32_16x16x32_bf16(Af[0], Bf[1][0], z4, 0,0,0);
      floatx4 a2 = __builtin_amdgcn_mfma_f32_16x16x32_bf16(Af[0], Bf[2][0], z4, 0,0,0);
      floatx4 a3 = __builtin_amdgcn_mfma_f32_16x16x32_bf16(Af[0], Bf[3][0], z4, 0,0,0);
      a0 = __builtin_amdgcn_mfma_f32_16x16x32_bf16(Af[1], Bf[0][1], a0, 0,0,0);
      a1 = __builtin_amdgcn_mfma_f32_16x16x32_bf16(Af[1], Bf[1][1], a1, 0,0,0);
      a2 = __builtin_amdgcn_mfma_f32_16x16x32_bf16(Af[1], Bf[2][1], a2, 0,0,0);
      a3 = __builtin_amdgcn_mfma_f32_16x16x32_bf16(Af[1], Bf[3][1], a3, 0,0,0);

      // consume pz[p] (loaded 4 steps ago), then reload for step s+4
      float z0 = a0[0] + bz[0] + bf2f((ushort_t)(pz[p].x & 0xffff));
      float z1 = a1[0] + bz[1] + bf2f((ushort_t)(pz[p].x >> 16));
      float z2 = a2[0] + bz[2] + bf2f((ushort_t)(pz[p].y & 0xffff));
      float z3 = a3[0] + bz[3] + bf2f((ushort_t)(pz[p].y >> 16));
      {
        int sn = s + 4; if (sn > TT-1) sn = TT-1;
        int tn = dir ? (TT-1-sn) : sn;
        pz[p] = *(const uint2*)(xzr + (size_t)tn*256);
      }

      {
        float ig = fsig(z0), fg = fsig(z1), og = fsig(z3);
        float gg = ftanh(z2);
        float cc = fg*cst + ig*gg;
        cst = cc;
        hl = og*ftanh(cc);
        Hbuf[nxt][q*4][u] = f2bf(hl);
      }
      ldsbar();
    }
  }
  h1last[(size_t)(cb*4 + q)*128 + dir*64 + u] = hl;
}

// ---------------- K4: dense head
__global__ __launch_bounds__(128) void k_head(
  const float* __restrict__ h1last,
  const float* __restrict__ d0W, const float* __restrict__ d0b,
  const float* __restrict__ d1W, const float* __restrict__ d1b,
  const float* __restrict__ oW,  const float* __restrict__ ob,
  float* __restrict__ outp)
{
  const int b = blockIdx.x;
  const int j = threadIdx.x;
  __shared__ float v0[128], v1[128];
  v0[j] = h1last[b*128 + j];
  __syncthreads();
  float acc = d0b[j];
  #pragma unroll
  for (int k=0;k<128;k++) acc += v0[k]*d0W[k*128 + j];
  v1[j] = fmaxf(acc, 0.f);
  __syncthreads();
  if (j < 64){
    float a2 = d1b[j];
    #pragma unroll
    for (int k=0;k<128;k++) a2 += v1[k]*d1W[k*64 + j];
    float p = fmaxf(a2, 0.f) * oW[j];
    #pragma unroll
    for (int off=32; off>0; off>>=1) p += __shfl_down(p, off, 64);
    if (j == 0) outp[b] = 1.f/(1.f + __expf(-(p + ob[0])));
  }
}

extern "C" void kernel_launch(void* const* d_in, const int* in_sizes, int n_in,
                              void* d_out, int out_size, void* d_ws, size_t ws_size,
                              hipStream_t stream)
{
  const float* x     = (const float*)d_in[0];
  const float* l0fWx = (const float*)d_in[1];
  const float* l0fWh = (const float*)d_in[2];
  const float* l0fb  = (const float*)d_in[3];
  const float* l0bWx = (const float*)d_in[4];
  const float* l0bWh = (const float*)d_in[5];
  const float* l0bb  = (const float*)d_in[6];
  const float* l1fWx = (const float*)d_in[7];
  const float* l1fWh = (const float*)d_in[8];
  const float* l1fb  = (const float*)d_in[9];
  const float* l1bWx = (const float*)d_in[10];
  const float* l1bWh = (const float*)d_in[11];
  const float* l1bb  = (const float*)d_in[12];
  const float* d0W = (const float*)d_in[13];
  const float* d0b = (const float*)d_in[14];
  const float* d1W = (const float*)d_in[15];
  const float* d1b = (const float*)d_in[16];
  const float* oW  = (const float*)d_in[17];
  const float* ob  = (const float*)d_in[18];
  float* outp = (float*)d_out;

  char* ws = (char*)d_ws;
  // Workspace budget: total use must stay within the r1-r7-proven 260,210,688 B.
  // xA (10,485,760 B) OVERLAPS the head of the xz1 region — lifetimes disjoint:
  // xA written by k_prep_xa, read only by k_lstm0m; xz1 written by k_xz1_gemm
  // which runs after k_lstm0m on the same stream.
  const size_t OFF_XT  = 0;                        // xc: 7,208,960 (slot 7,864,320)
  const size_t OFF_H0  = OFF_XT  + 7864320ull;     // 83,886,080
  const size_t OFF_XZ  = OFF_H0  + 83886080ull;    // 167,772,160 (xz1R; xA overlaps head)
  const size_t OFF_XA  = OFF_XZ;                   // xA: 10,485,760 (dead before xz1 written)
  const size_t OFF_WT  = OFF_XZ  + 167772160ull;   // 262,144
  const size_t OFF_B0  = OFF_WT  + 262144ull;      // 327,680
  const size_t OFF_B1  = OFF_B0  + 327680ull;      // 65,536
  const size_t OFF_H1  = OFF_B1  + 65536ull;       // 32,768  -> total 260,210,688

  ushort_t* xc  = (ushort_t*)(ws + OFF_XT);
  ushort_t* h0  = (ushort_t*)(ws + OFF_H0);
  ushort_t* xz1 = (ushort_t*)(ws + OFF_XZ);
  ushort_t* xA  = (ushort_t*)(ws + OFF_XA);
  ushort_t* WT  = (ushort_t*)(ws + OFF_WT);
  ushort_t* B0T = (ushort_t*)(ws + OFF_B0);
  ushort_t* B1T = (ushort_t*)(ws + OFF_B1);
  float*    h1l = (float*)(ws + OFF_H1);

  hipLaunchKernelGGL(k_convert_x,   dim3(3520), dim3(256), 0, stream, x, xc);
  hipLaunchKernelGGL(k_prep_xa,     dim3(2560), dim3(256), 0, stream, xc, xA);
  hipLaunchKernelGGL(k_prep_l0,     dim3(640),  dim3(256), 0, stream, l0fWx, l0fWh, l0bWx, l0bWh, B0T);
  hipLaunchKernelGGL(k_prep_l1,     dim3(128),  dim3(256), 0, stream, l1fWh, l1bWh, B1T);
  hipLaunchKernelGGL(k_prep_wxT,    dim3(512),  dim3(256), 0, stream, l1fWx, l1bWx, WT);
  hipLaunchKernelGGL(k_lstm0m,      dim3(32),   dim3(512), 0, stream, xA, B0T, l0fb, l0bb, h0);
  hipLaunchKernelGGL(k_xz1_gemm,    dim3(1280,2), dim3(512), 0, stream, h0, WT, xz1);
  hipLaunchKernelGGL(k_lstm1m,      dim3(32),   dim3(256), 0, stream, xz1, B1T, l1fb, l1bb, h1l);
  hipLaunchKernelGGL(k_head,        dim3(64),   dim3(128), 0, stream,
                     h1l, d0W, d0b, d1W, d1b, oW, ob, outp);
}

// Round 10
// 3148.118 us; speedup vs baseline: 1.0691x; 1.0691x over previous
//
#include <hip/hip_runtime.h>
#include <stdint.h>

#define TT 2560
#define BB 64
#define CC 22

typedef unsigned short ushort_t;
typedef __attribute__((ext_vector_type(4))) float floatx4;
typedef __attribute__((ext_vector_type(8))) short bf16x8;

__device__ __forceinline__ float bf2f(ushort_t u){
  union { uint32_t i; float f; } v; v.i = ((uint32_t)u) << 16; return v.f;
}
__device__ __forceinline__ ushort_t f2bf(float f){
  union { float f; uint32_t i; } v; v.f = f;
  uint32_t r = v.i + 0x7FFFu + ((v.i >> 16) & 1u);
  return (ushort_t)(r >> 16);
}
__device__ __forceinline__ float fsig(float x){ return 1.f/(1.f + __expf(-x)); }
__device__ __forceinline__ float ftanh(float x){ return 2.f/(1.f + __expf(-2.f*x)) - 1.f; }

// LDS-only barrier: does NOT drain vmcnt; global stores/prefetch loads stay in
// flight across the 2560-step serial loop.
__device__ __forceinline__ void ldsbar(){
  asm volatile("s_waitcnt lgkmcnt(0)\n\ts_barrier" ::: "memory");
}

// ---------------- K0a: cast x [B][C][T] fp32 -> xc [B][C][T] bf16 (time-contiguous)
__global__ __launch_bounds__(256) void k_convert_x(const float* __restrict__ x, ushort_t* __restrict__ xc){
  int i4 = blockIdx.x*256 + threadIdx.x;
  if (i4 >= BB*CC*TT/4) return;
  const float4 v = ((const float4*)x)[i4];
  uint2 o;
  o.x = (uint32_t)f2bf(v.x) | ((uint32_t)f2bf(v.y) << 16);
  o.y = (uint32_t)f2bf(v.z) | ((uint32_t)f2bf(v.w) << 16);
  ((uint2*)xc)[i4] = o;
}

// ---------------- K0a2: pack x into MFMA A-fragment order.
// xA[cb][t][l16] (16B each): l16 = c4*4+q -> lane (m=c4*4..c4*4+3, q); elems j: channel c=q*8+j
__global__ __launch_bounds__(256) void k_prep_xa(const ushort_t* __restrict__ xc, ushort_t* __restrict__ xA){
  int idx = blockIdx.x*256 + threadIdx.x;          // (cb*TT + t)*16 + l16
  if (idx >= 16*TT*16) return;
  int l16 = idx & 15;
  int rest = idx >> 4;
  int t = rest % TT, cb = rest / TT;
  int c4 = l16 >> 2, q = l16 & 3;
  int b = cb*4 + c4;
  ushort_t v[8];
  #pragma unroll
  for (int j=0;j<8;j++){
    int c = q*8 + j;
    v[j] = (c < CC) ? xc[((size_t)b*CC + c)*TT + t] : (ushort_t)0;
  }
  *(uint4*)(xA + (size_t)idx*8) = *(const uint4*)v;
}

// ---------------- K0b: B0T[dir][n=512][k=160]: k<128 Wh0[k][n]; 128..149 Wx0[k-128][n]; else 0
__global__ __launch_bounds__(256) void k_prep_l0(const float* __restrict__ WxF, const float* __restrict__ WhF,
                                                 const float* __restrict__ WxB, const float* __restrict__ WhB,
                                                 ushort_t* __restrict__ B0T){
  int idx = blockIdx.x*256 + threadIdx.x;
  if (idx >= 2*512*160) return;
  int dir = idx / 81920; int r = idx % 81920; int n = r / 160; int k = r % 160;
  const float* Wh = dir ? WhB : WhF;
  const float* Wx = dir ? WxB : WxF;
  float v = (k < 128) ? Wh[k*512 + n] : (((k-128) < CC) ? Wx[(k-128)*512 + n] : 0.f);
  B0T[idx] = f2bf(v);
}

// ---------------- K0c: B1T[dir][n=256][k=64] = Wh1[k][n]
__global__ __launch_bounds__(256) void k_prep_l1(const float* __restrict__ WhF, const float* __restrict__ WhB,
                                                 ushort_t* __restrict__ B1T){
  int idx = blockIdx.x*256 + threadIdx.x;
  if (idx >= 2*256*64) return;
  int dir = idx >> 14; int r = idx & 16383; int n = r >> 6; int k = r & 63;
  const float* Wh = dir ? WhB : WhF;
  B1T[idx] = f2bf(Wh[k*256 + n]);
}

// ---------------- K0d: WT[dir][n=256][k=256] = Wx1[k][n]  (for xz1 gemm)
__global__ __launch_bounds__(256) void k_prep_wxT(const float* __restrict__ Wf, const float* __restrict__ Wb,
                                                  ushort_t* __restrict__ WT){
  int idx = blockIdx.x*256 + threadIdx.x;
  int dir = idx >> 16; int r = idx & 65535; int n = r >> 8; int k = r & 255;
  const float* W = dir ? Wb : Wf;
  WT[idx] = f2bf(W[k*256 + n]);
}

// ---------------- K1: layer-0 MFMA scan. 4 chains/WG, 8 waves (2/SIMD), 32 WGs.
// h k-tiles (0..3) from LDS; x k-tile from UNCONDITIONAL per-lane global-prefetched
// registers (lanes m%4!=0 load a broadcast duplicate; their A-rows feed only
// C-rows we never read, so no zeroing/divergence needed).
__global__ __launch_bounds__(512, 2) void k_lstm0m(
  const ushort_t* __restrict__ xA, const ushort_t* __restrict__ B0T,
  const float* __restrict__ bF, const float* __restrict__ bB,
  ushort_t* __restrict__ h0seq)                     // [B][T][256]: fwd 0..127, bwd 128..255
{
  const int dir = blockIdx.x & 1, cb = blockIdx.x >> 1;   // cb 0..15
  const int tid = threadIdx.x;
  const int wv = tid >> 6, lane = tid & 63, m = lane & 15, q = lane >> 4;
  const int u = wv*16 + m;                                // unit 0..127
  const float* bi = dir ? bB : bF;

  __shared__ __align__(16) ushort_t Abuf[2][16][136];  // rows 4q: h 0..127 | 8 pad

  bf16x8 Bf[4][5];                                     // [gate][ktile] register-resident
  const ushort_t* Bb = B0T + (size_t)dir*512*160;
  #pragma unroll
  for (int g=0; g<4; g++){
    int nt = g*8 + wv;
    #pragma unroll
    for (int kt=0; kt<5; kt++)
      Bf[g][kt] = *(const bf16x8*)(Bb + (size_t)(nt*16+m)*160 + kt*32 + q*8);
  }
  float bz[4];
  #pragma unroll
  for (int g=0; g<4; g++) bz[g] = bi[g*128 + u];

  for (int i = tid; i < (int)(sizeof(Abuf)/4); i += 512) ((uint32_t*)Abuf)[i] = 0u;

  // x fragment stream: ALL lanes load (m 0..3 share an address -> HW broadcast)
  const ushort_t* xap = xA + (((size_t)cb*TT)*16 + (size_t)((m>>2)*4 + q))*8;
  uint4 px[4];
  #pragma unroll
  for (int j=0; j<4; j++){
    int tj = dir ? (TT-1-j) : j;
    px[j] = *(const uint4*)(xap + (size_t)tj*128);
  }
  __syncthreads();

  const floatx4 z4 = {0.f,0.f,0.f,0.f};   // persistent zero C-operand
  float cst = 0.f;
  const int t00 = dir ? TT-1 : 0;
  ushort_t* hp = h0seq + ((size_t)(cb*4 + q)*TT + t00)*256 + dir*128 + u;
  const int hstep = dir ? -256 : 256;

  for (int i = 0; i < TT/4; ++i){
    #pragma unroll
    for (int p = 0; p < 4; ++p){
      const int s = i*4 + p;
      const int cur = s & 1, nxt = cur ^ 1;

      bf16x8 Af[4];
      const ushort_t* ar = &Abuf[cur][m][0];
      #pragma unroll
      for (int kt=0; kt<4; kt++) Af[kt] = *(const bf16x8*)(ar + kt*32 + q*8);
      bf16x8 Ax = *(const bf16x8*)&px[p];

      floatx4 a[4];
      #pragma unroll
      for (int g=0; g<4; g++)                // x k-tile FIRST (its wait is long satisfied)
        a[g] = __builtin_amdgcn_mfma_f32_16x16x32_bf16(Ax, Bf[g][4], z4, 0,0,0);
      #pragma unroll
      for (int kt=0; kt<4; kt++)
        #pragma unroll
        for (int g=0; g<4; g++)
          a[g] = __builtin_amdgcn_mfma_f32_16x16x32_bf16(Af[kt], Bf[g][kt], a[g], 0,0,0);

      // reload px[p] for step s+4 (unconditional, consumed-then-reload)
      {
        int sn = s + 4; if (sn > TT-1) sn = TT-1;
        int tn = dir ? (TT-1-sn) : sn;
        px[p] = *(const uint4*)(xap + (size_t)tn*128);
      }

      {  // one gate-set per lane: unit u, chain q
        float ig = fsig (a[0][0] + bz[0]);
        float fg = fsig (a[1][0] + bz[1]);
        float gg = ftanh(a[2][0] + bz[2]);
        float og = fsig (a[3][0] + bz[3]);
        float cc = fg*cst + ig*gg;
        cst = cc;
        ushort_t hv = f2bf(og*ftanh(cc));
        Abuf[nxt][q*4][u] = hv;
        *hp = hv; hp += hstep;              // fire-and-forget
      }
      ldsbar();
    }
  }
}

// ---------------- K2: xz1R[dir][b][t][u(64)][g(4)] = bf16( h0seq[bt][:256] @ Wx1[dir] )
__global__ __launch_bounds__(512) void k_xz1_gemm(const ushort_t* __restrict__ h0seq,
                                                  const ushort_t* __restrict__ WxT,
                                                  ushort_t* __restrict__ xz1)
{
  const int mb  = blockIdx.x;
  const int dir = blockIdx.y;
  const ushort_t* W   = WxT + (size_t)dir*256*256;
  ushort_t*       out = xz1 + (size_t)dir*BB*TT*256;
  const int wave = threadIdx.x >> 6;
  const int lane = threadIdx.x & 63;
  const int mw = wave & 3;
  const int nw = wave >> 2;       // n-half: gates {2nw, 2nw+1}
  const int m_ = lane & 15;
  const int q_ = lane >> 4;

  floatx4 acc[2][8];
  #pragma unroll
  for (int a=0;a<2;a++)
    #pragma unroll
    for (int n=0;n<8;n++) acc[a][n] = (floatx4)0.f;

  const size_t Abase = ((size_t)mb*128 + mw*32 + m_)*256 + q_*8;
  const size_t Bbase = ((size_t)nw*128 + m_)*256 + q_*8;

  for (int kc = 0; kc < 256; kc += 32){
    bf16x8 afr[2];
    #pragma unroll
    for (int mt=0;mt<2;mt++)
      afr[mt] = *(const bf16x8*)(h0seq + Abase + (size_t)mt*16*256 + kc);
    #pragma unroll
    for (int nt=0;nt<8;nt++){
      bf16x8 bfr = *(const bf16x8*)(W + Bbase + (size_t)nt*16*256 + kc);
      #pragma unroll
      for (int mt=0;mt<2;mt++)
        acc[mt][nt] = __builtin_amdgcn_mfma_f32_16x16x32_bf16(afr[mt], bfr, acc[mt][nt], 0,0,0);
    }
  }
  #pragma unroll
  for (int mt=0;mt<2;mt++)
    #pragma unroll
    for (int r=0;r<4;r++){
      size_t bt = (size_t)mb*128 + mw*32 + mt*16 + q_*4 + r;
      ushort_t* rowp = out + bt*256;
      #pragma unroll
      for (int wvz=0; wvz<4; wvz++){
        uint32_t lo = f2bf(acc[mt][wvz][r]);
        uint32_t hi = f2bf(acc[mt][wvz+4][r]);
        *(uint32_t*)(rowp + (wvz*16+m_)*4 + 2*nw) = lo | (hi << 16);
      }
    }
}

// ---------------- K3: layer-1 MFMA scan, fwd+bwd MERGED per WG (waves 0-3 fwd,
// 4-7 bwd -> 2 waves/SIMD hide each other's latency). 4 chains/WG/dir, 16 WGs.
__global__ __launch_bounds__(512, 1) void k_lstm1m(
  const ushort_t* __restrict__ xz1R,                // [dir][b][t][u][g] bf16
  const ushort_t* __restrict__ B1T,                 // [dir][n=256][k=64] bf16
  const float* __restrict__ bF, const float* __restrict__ bB,
  float* __restrict__ h1last)                       // [B][128]: fwd 0..63, bwd 64..127
{
  const int cb = blockIdx.x;                              // cb 0..15
  const int tid = threadIdx.x;
  const int wv = tid >> 6, lane = tid & 63, m = lane & 15, q = lane >> 4;
  const int dir = wv >> 2, wl = wv & 3;
  const int u = wl*16 + m;                                // unit 0..63
  const float* bi = dir ? bB : bF;

  __shared__ __align__(16) ushort_t Hbuf[2][2][16][88];   // [dir][buf]

  bf16x8 Bf[4][2];                        // gate g -> n-tile g*4+wl
  const ushort_t* Bb = B1T + (size_t)dir*256*64;
  #pragma unroll
  for (int g=0; g<4; g++){
    int nt = g*4 + wl;
    #pragma unroll
    for (int kt=0; kt<2; kt++)
      Bf[g][kt] = *(const bf16x8*)(Bb + (size_t)(nt*16+m)*64 + kt*32 + q*8);
  }
  float bz[4];
  #pragma unroll
  for (int g=0; g<4; g++) bz[g] = bi[g*64 + u];

  for (int i = tid; i < (int)(sizeof(Hbuf)/4); i += 512) ((uint32_t*)Hbuf)[i] = 0u;

  const ushort_t* xzr = xz1R + ((size_t)dir*BB + (size_t)(cb*4+q))*TT*256 + (size_t)u*4;
  uint2 pz[4];
  #pragma unroll
  for (int j=0; j<4; j++){
    int tj = dir ? (TT-1-j) : j;
    pz[j] = *(const uint2*)(xzr + (size_t)tj*256);
  }
  __syncthreads();

  const floatx4 z4 = {0.f,0.f,0.f,0.f};
  float cst = 0.f, hl = 0.f;

  for (int i = 0; i < TT/4; ++i){
    #pragma unroll
    for (int p = 0; p < 4; ++p){
      const int s = i*4 + p;
      const int cur = s & 1, nxt = cur ^ 1;

      bf16x8 Af[2];
      const ushort_t* ar = &Hbuf[dir][cur][m][0];
      Af[0] = *(const bf16x8*)(ar + q*8);
      Af[1] = *(const bf16x8*)(ar + 32 + q*8);

      floatx4 a0 = __builtin_amdgcn_mfma_f32_16x16x32_bf16(Af[0], Bf[0][0], z4, 0,0,0);
      floatx4 a1 = __builtin_amdgcn_mfma_f32_16x16x32_bf16(Af[0], Bf[1][0], z4, 0,0,0);
      floatx4 a2 = __builtin_amdgcn_mfma_f32_16x16x32_bf16(Af[0], Bf[2][0], z4, 0,0,0);
      floatx4 a3 = __builtin_amdgcn_mfma_f32_16x16x32_bf16(Af[0], Bf[3][0], z4, 0,0,0);
      a0 = __builtin_amdgcn_mfma_f32_16x16x32_bf16(Af[1], Bf[0][1], a0, 0,0,0);
      a1 = __builtin_amdgcn_mfma_f32_16x16x32_bf16(Af[1], Bf[1][1], a1, 0,0,0);
      a2 = __builtin_amdgcn_mfma_f32_16x16x32_bf16(Af[1], Bf[2][1], a2, 0,0,0);
      a3 = __builtin_amdgcn_mfma_f32_16x16x32_bf16(Af[1], Bf[3][1], a3, 0,0,0);

      // consume pz[p] (loaded 4 steps ago), then reload for step s+4
      float z0 = a0[0] + bz[0] + bf2f((ushort_t)(pz[p].x & 0xffff));
      float z1 = a1[0] + bz[1] + bf2f((ushort_t)(pz[p].x >> 16));
      float z2 = a2[0] + bz[2] + bf2f((ushort_t)(pz[p].y & 0xffff));
      float z3 = a3[0] + bz[3] + bf2f((ushort_t)(pz[p].y >> 16));
      {
        int sn = s + 4; if (sn > TT-1) sn = TT-1;
        int tn = dir ? (TT-1-sn) : sn;
        pz[p] = *(const uint2*)(xzr + (size_t)tn*256);
      }

      {
        float ig = fsig(z0), fg = fsig(z1), og = fsig(z3);
        float gg = ftanh(z2);
        float cc = fg*cst + ig*gg;
        cst = cc;
        hl = og*ftanh(cc);
        Hbuf[dir][nxt][q*4][u] = f2bf(hl);
      }
      ldsbar();
    }
  }
  h1last[(size_t)(cb*4 + q)*128 + dir*64 + u] = hl;
}

// ---------------- K4: dense head
__global__ __launch_bounds__(128) void k_head(
  const float* __restrict__ h1last,
  const float* __restrict__ d0W, const float* __restrict__ d0b,
  const float* __restrict__ d1W, const float* __restrict__ d1b,
  const float* __restrict__ oW,  const float* __restrict__ ob,
  float* __restrict__ outp)
{
  const int b = blockIdx.x;
  const int j = threadIdx.x;
  __shared__ float v0[128], v1[128];
  v0[j] = h1last[b*128 + j];
  __syncthreads();
  float acc = d0b[j];
  #pragma unroll
  for (int k=0;k<128;k++) acc += v0[k]*d0W[k*128 + j];
  v1[j] = fmaxf(acc, 0.f);
  __syncthreads();
  if (j < 64){
    float a2 = d1b[j];
    #pragma unroll
    for (int k=0;k<128;k++) a2 += v1[k]*d1W[k*64 + j];
    float p = fmaxf(a2, 0.f) * oW[j];
    #pragma unroll
    for (int off=32; off>0; off>>=1) p += __shfl_down(p, off, 64);
    if (j == 0) outp[b] = 1.f/(1.f + __expf(-(p + ob[0])));
  }
}

extern "C" void kernel_launch(void* const* d_in, const int* in_sizes, int n_in,
                              void* d_out, int out_size, void* d_ws, size_t ws_size,
                              hipStream_t stream)
{
  const float* x     = (const float*)d_in[0];
  const float* l0fWx = (const float*)d_in[1];
  const float* l0fWh = (const float*)d_in[2];
  const float* l0fb  = (const float*)d_in[3];
  const float* l0bWx = (const float*)d_in[4];
  const float* l0bWh = (const float*)d_in[5];
  const float* l0bb  = (const float*)d_in[6];
  const float* l1fWx = (const float*)d_in[7];
  const float* l1fWh = (const float*)d_in[8];
  const float* l1fb  = (const float*)d_in[9];
  const float* l1bWx = (const float*)d_in[10];
  const float* l1bWh = (const float*)d_in[11];
  const float* l1bb  = (const float*)d_in[12];
  const float* d0W = (const float*)d_in[13];
  const float* d0b = (const float*)d_in[14];
  const float* d1W = (const float*)d_in[15];
  const float* d1b = (const float*)d_in[16];
  const float* oW  = (const float*)d_in[17];
  const float* ob  = (const float*)d_in[18];
  float* outp = (float*)d_out;

  char* ws = (char*)d_ws;
  // Workspace: total 260,210,688 B (r1-r7-proven budget).
  // xA (10,485,760 B) overlaps the head of the xz1 region — lifetimes disjoint
  // (xA read only by k_lstm0m; xz1 written by k_xz1_gemm afterwards).
  const size_t OFF_XT  = 0;                        // xc: 7,208,960 (slot 7,864,320)
  const size_t OFF_H0  = OFF_XT  + 7864320ull;     // 83,886,080
  const size_t OFF_XZ  = OFF_H0  + 83886080ull;    // 167,772,160 (xz1R; xA overlaps head)
  const size_t OFF_XA  = OFF_XZ;                   // xA: 10,485,760 (dead before xz1 written)
  const size_t OFF_WT  = OFF_XZ  + 167772160ull;   // 262,144
  const size_t OFF_B0  = OFF_WT  + 262144ull;      // 327,680
  const size_t OFF_B1  = OFF_B0  + 327680ull;      // 65,536
  const size_t OFF_H1  = OFF_B1  + 65536ull;       // 32,768

  ushort_t* xc  = (ushort_t*)(ws + OFF_XT);
  ushort_t* h0  = (ushort_t*)(ws + OFF_H0);
  ushort_t* xz1 = (ushort_t*)(ws + OFF_XZ);
  ushort_t* xA  = (ushort_t*)(ws + OFF_XA);
  ushort_t* WT  = (ushort_t*)(ws + OFF_WT);
  ushort_t* B0T = (ushort_t*)(ws + OFF_B0);
  ushort_t* B1T = (ushort_t*)(ws + OFF_B1);
  float*    h1l = (float*)(ws + OFF_H1);

  hipLaunchKernelGGL(k_convert_x,   dim3(3520), dim3(256), 0, stream, x, xc);
  hipLaunchKernelGGL(k_prep_xa,     dim3(2560), dim3(256), 0, stream, xc, xA);
  hipLaunchKernelGGL(k_prep_l0,     dim3(640),  dim3(256), 0, stream, l0fWx, l0fWh, l0bWx, l0bWh, B0T);
  hipLaunchKernelGGL(k_prep_l1,     dim3(128),  dim3(256), 0, stream, l1fWh, l1bWh, B1T);
  hipLaunchKernelGGL(k_prep_wxT,    dim3(512),  dim3(256), 0, stream, l1fWx, l1bWx, WT);
  hipLaunchKernelGGL(k_lstm0m,      dim3(32),   dim3(512), 0, stream, xA, B0T, l0fb, l0bb, h0);
  hipLaunchKernelGGL(k_xz1_gemm,    dim3(1280,2), dim3(512), 0, stream, h0, WT, xz1);
  hipLaunchKernelGGL(k_lstm1m,      dim3(16),   dim3(512), 0, stream, xz1, B1T, l1fb, l1bb, h1l);
  hipLaunchKernelGGL(k_head,        dim3(64),   dim3(128), 0, stream,
                     h1l, d0W, d0b, d1W, d1b, oW, ob, outp);
}

// Round 11
// 2681.998 us; speedup vs baseline: 1.2549x; 1.1738x over previous
//
#include <hip/hip_runtime.h>
#include <stdint.h>

#define TT 2560
#define BB 64
#define CC 22

typedef unsigned short ushort_t;
typedef __attribute__((ext_vector_type(4))) float floatx4;
typedef __attribute__((ext_vector_type(8))) short bf16x8;

__device__ __forceinline__ float bf2f(ushort_t u){
  union { uint32_t i; float f; } v; v.i = ((uint32_t)u) << 16; return v.f;
}
__device__ __forceinline__ ushort_t f2bf(float f){
  union { float f; uint32_t i; } v; v.f = f;
  uint32_t r = v.i + 0x7FFFu + ((v.i >> 16) & 1u);
  return (ushort_t)(r >> 16);
}
__device__ __forceinline__ float fsig(float x){ return 1.f/(1.f + __expf(-x)); }
__device__ __forceinline__ float ftanh(float x){ return 2.f/(1.f + __expf(-2.f*x)) - 1.f; }

// LDS-only barrier: does NOT drain vmcnt; global stores/prefetch loads stay in
// flight across the 2560-step serial loop.
__device__ __forceinline__ void ldsbar(){
  asm volatile("s_waitcnt lgkmcnt(0)\n\ts_barrier" ::: "memory");
}

// ---------------- K0a: cast x [B][C][T] fp32 -> xc [B][C][T] bf16 (time-contiguous)
__global__ __launch_bounds__(256) void k_convert_x(const float* __restrict__ x, ushort_t* __restrict__ xc){
  int i4 = blockIdx.x*256 + threadIdx.x;
  if (i4 >= BB*CC*TT/4) return;
  const float4 v = ((const float4*)x)[i4];
  uint2 o;
  o.x = (uint32_t)f2bf(v.x) | ((uint32_t)f2bf(v.y) << 16);
  o.y = (uint32_t)f2bf(v.z) | ((uint32_t)f2bf(v.w) << 16);
  ((uint2*)xc)[i4] = o;
}

// ---------------- K0a2: pack x into MFMA A-fragment order.
// xA[cb][t][l16] (16B each): l16 = c4*4+q -> lane (m=c4*4..c4*4+3, q); elems j: channel c=q*8+j
__global__ __launch_bounds__(256) void k_prep_xa(const ushort_t* __restrict__ xc, ushort_t* __restrict__ xA){
  int idx = blockIdx.x*256 + threadIdx.x;          // (cb*TT + t)*16 + l16
  if (idx >= 16*TT*16) return;
  int l16 = idx & 15;
  int rest = idx >> 4;
  int t = rest % TT, cb = rest / TT;
  int c4 = l16 >> 2, q = l16 & 3;
  int b = cb*4 + c4;
  ushort_t v[8];
  #pragma unroll
  for (int j=0;j<8;j++){
    int c = q*8 + j;
    v[j] = (c < CC) ? xc[((size_t)b*CC + c)*TT + t] : (ushort_t)0;
  }
  *(uint4*)(xA + (size_t)idx*8) = *(const uint4*)v;
}

// ---------------- K0b: B0T[dir][n=512][k=160]: k<128 Wh0[k][n]; 128..149 Wx0[k-128][n]; else 0
__global__ __launch_bounds__(256) void k_prep_l0(const float* __restrict__ WxF, const float* __restrict__ WhF,
                                                 const float* __restrict__ WxB, const float* __restrict__ WhB,
                                                 ushort_t* __restrict__ B0T){
  int idx = blockIdx.x*256 + threadIdx.x;
  if (idx >= 2*512*160) return;
  int dir = idx / 81920; int r = idx % 81920; int n = r / 160; int k = r % 160;
  const float* Wh = dir ? WhB : WhF;
  const float* Wx = dir ? WxB : WxF;
  float v = (k < 128) ? Wh[k*512 + n] : (((k-128) < CC) ? Wx[(k-128)*512 + n] : 0.f);
  B0T[idx] = f2bf(v);
}

// ---------------- K0c: B1T[dir][n=256][k=64] = Wh1[k][n]
__global__ __launch_bounds__(256) void k_prep_l1(const float* __restrict__ WhF, const float* __restrict__ WhB,
                                                 ushort_t* __restrict__ B1T){
  int idx = blockIdx.x*256 + threadIdx.x;
  if (idx >= 2*256*64) return;
  int dir = idx >> 14; int r = idx & 16383; int n = r >> 6; int k = r & 63;
  const float* Wh = dir ? WhB : WhF;
  B1T[idx] = f2bf(Wh[k*256 + n]);
}

// ---------------- K0d: WT[dir][n=256][k=256] = Wx1[k][n]  (for xz1 gemm)
__global__ __launch_bounds__(256) void k_prep_wxT(const float* __restrict__ Wf, const float* __restrict__ Wb,
                                                  ushort_t* __restrict__ WT){
  int idx = blockIdx.x*256 + threadIdx.x;
  int dir = idx >> 16; int r = idx & 65535; int n = r >> 8; int k = r & 255;
  const float* W = dir ? Wb : Wf;
  WT[idx] = f2bf(W[k*256 + n]);
}

// ---------------- K1: layer-0 MFMA scan. 4 chains/WG, 8 waves (2/SIMD), 32 WGs.
// h k-tiles from LDS with BROADCAST row reads (row m&~3: rows whose C-rows are
// unread get duplicate data -> 4-lane same-address broadcast, conflicts ~0);
// x k-tile from unconditional per-lane global-prefetched registers.
__global__ __launch_bounds__(512, 2) void k_lstm0m(
  const ushort_t* __restrict__ xA, const ushort_t* __restrict__ B0T,
  const float* __restrict__ bF, const float* __restrict__ bB,
  ushort_t* __restrict__ h0seq)                     // [B][T][256]: fwd 0..127, bwd 128..255
{
  const int dir = blockIdx.x & 1, cb = blockIdx.x >> 1;   // cb 0..15
  const int tid = threadIdx.x;
  const int wv = tid >> 6, lane = tid & 63, m = lane & 15, q = lane >> 4;
  const int u = wv*16 + m;                                // unit 0..127
  const float* bi = dir ? bB : bF;

  __shared__ __align__(16) ushort_t Abuf[2][16][136];  // rows 4q: h 0..127 | 8 pad

  bf16x8 Bf[4][5];                                     // [gate][ktile] register-resident
  const ushort_t* Bb = B0T + (size_t)dir*512*160;
  #pragma unroll
  for (int g=0; g<4; g++){
    int nt = g*8 + wv;
    #pragma unroll
    for (int kt=0; kt<5; kt++)
      Bf[g][kt] = *(const bf16x8*)(Bb + (size_t)(nt*16+m)*160 + kt*32 + q*8);
  }
  float bz[4];
  #pragma unroll
  for (int g=0; g<4; g++) bz[g] = bi[g*128 + u];

  for (int i = tid; i < (int)(sizeof(Abuf)/4); i += 512) ((uint32_t*)Abuf)[i] = 0u;

  // x fragment stream: ALL lanes load (m 0..3 share an address -> HW broadcast)
  const ushort_t* xap = xA + (((size_t)cb*TT)*16 + (size_t)((m>>2)*4 + q))*8;
  uint4 px[4];
  #pragma unroll
  for (int j=0; j<4; j++){
    int tj = dir ? (TT-1-j) : j;
    px[j] = *(const uint4*)(xap + (size_t)tj*128);
  }
  __syncthreads();

  const floatx4 z4 = {0.f,0.f,0.f,0.f};   // persistent zero C-operand
  float cst = 0.f;
  const int t00 = dir ? TT-1 : 0;
  ushort_t* hp = h0seq + ((size_t)(cb*4 + q)*TT + t00)*256 + dir*128 + u;
  const int hstep = dir ? -256 : 256;

  const int mb = m & ~3;                   // broadcast source row (chain (m>>2))

  for (int i = 0; i < TT/4; ++i){
    #pragma unroll
    for (int p = 0; p < 4; ++p){
      const int s = i*4 + p;
      const int cur = s & 1, nxt = cur ^ 1;

      bf16x8 Af[4];
      const ushort_t* ar = &Abuf[cur][mb][0];
      #pragma unroll
      for (int kt=0; kt<4; kt++) Af[kt] = *(const bf16x8*)(ar + kt*32 + q*8);
      bf16x8 Ax = *(const bf16x8*)&px[p];

      floatx4 a[4];
      #pragma unroll
      for (int g=0; g<4; g++)                // x k-tile FIRST (its wait is long satisfied)
        a[g] = __builtin_amdgcn_mfma_f32_16x16x32_bf16(Ax, Bf[g][4], z4, 0,0,0);
      #pragma unroll
      for (int kt=0; kt<4; kt++)
        #pragma unroll
        for (int g=0; g<4; g++)
          a[g] = __builtin_amdgcn_mfma_f32_16x16x32_bf16(Af[kt], Bf[g][kt], a[g], 0,0,0);

      // reload px[p] for step s+4 (unconditional, consumed-then-reload)
      {
        int sn = s + 4; if (sn > TT-1) sn = TT-1;
        int tn = dir ? (TT-1-sn) : sn;
        px[p] = *(const uint4*)(xap + (size_t)tn*128);
      }

      {  // one gate-set per lane: unit u, chain q
        float ig = fsig (a[0][0] + bz[0]);
        float fg = fsig (a[1][0] + bz[1]);
        float gg = ftanh(a[2][0] + bz[2]);
        float og = fsig (a[3][0] + bz[3]);
        float cc = fg*cst + ig*gg;
        cst = cc;
        ushort_t hv = f2bf(og*ftanh(cc));
        Abuf[nxt][q*4][u] = hv;
        *hp = hv; hp += hstep;              // fire-and-forget
      }
      ldsbar();
    }
  }
}

// ---------------- K2: xz1R[dir][b][t][u(64)][g(4)] = bf16( h0seq[bt][:256] @ Wx1[dir] )
__global__ __launch_bounds__(512) void k_xz1_gemm(const ushort_t* __restrict__ h0seq,
                                                  const ushort_t* __restrict__ WxT,
                                                  ushort_t* __restrict__ xz1)
{
  const int mb  = blockIdx.x;
  const int dir = blockIdx.y;
  const ushort_t* W   = WxT + (size_t)dir*256*256;
  ushort_t*       out = xz1 + (size_t)dir*BB*TT*256;
  const int wave = threadIdx.x >> 6;
  const int lane = threadIdx.x & 63;
  const int mw = wave & 3;
  const int nw = wave >> 2;       // n-half: gates {2nw, 2nw+1}
  const int m_ = lane & 15;
  const int q_ = lane >> 4;

  floatx4 acc[2][8];
  #pragma unroll
  for (int a=0;a<2;a++)
    #pragma unroll
    for (int n=0;n<8;n++) acc[a][n] = (floatx4)0.f;

  const size_t Abase = ((size_t)mb*128 + mw*32 + m_)*256 + q_*8;
  const size_t Bbase = ((size_t)nw*128 + m_)*256 + q_*8;

  for (int kc = 0; kc < 256; kc += 32){
    bf16x8 afr[2];
    #pragma unroll
    for (int mt=0;mt<2;mt++)
      afr[mt] = *(const bf16x8*)(h0seq + Abase + (size_t)mt*16*256 + kc);
    #pragma unroll
    for (int nt=0;nt<8;nt++){
      bf16x8 bfr = *(const bf16x8*)(W + Bbase + (size_t)nt*16*256 + kc);
      #pragma unroll
      for (int mt=0;mt<2;mt++)
        acc[mt][nt] = __builtin_amdgcn_mfma_f32_16x16x32_bf16(afr[mt], bfr, acc[mt][nt], 0,0,0);
    }
  }
  #pragma unroll
  for (int mt=0;mt<2;mt++)
    #pragma unroll
    for (int r=0;r<4;r++){
      size_t bt = (size_t)mb*128 + mw*32 + mt*16 + q_*4 + r;
      ushort_t* rowp = out + bt*256;
      #pragma unroll
      for (int wvz=0; wvz<4; wvz++){
        uint32_t lo = f2bf(acc[mt][wvz][r]);
        uint32_t hi = f2bf(acc[mt][wvz+4][r]);
        *(uint32_t*)(rowp + (wvz*16+m_)*4 + 2*nw) = lo | (hi << 16);
      }
    }
}

// ---------------- K3: layer-1 MFMA scan. 4 chains/WG, 4 waves, 32 WGs (split dirs —
// r10's merged-dir variant regressed: shared barrier couples independent recurrences).
__global__ __launch_bounds__(256, 1) void k_lstm1m(
  const ushort_t* __restrict__ xz1R,                // [dir][b][t][u][g] bf16
  const ushort_t* __restrict__ B1T,                 // [dir][n=256][k=64] bf16
  const float* __restrict__ bF, const float* __restrict__ bB,
  float* __restrict__ h1last)                       // [B][128]: fwd 0..63, bwd 64..127
{
  const int dir = blockIdx.x & 1, cb = blockIdx.x >> 1;   // cb 0..15
  const int tid = threadIdx.x;
  const int wv = tid >> 6, lane = tid & 63, m = lane & 15, q = lane >> 4;
  const int u = wv*16 + m;                                // unit 0..63
  const float* bi = dir ? bB : bF;

  __shared__ __align__(16) ushort_t Hbuf[2][16][88];

  bf16x8 Bf[4][2];                        // gate g -> n-tile g*4+wv
  const ushort_t* Bb = B1T + (size_t)dir*256*64;
  #pragma unroll
  for (int g=0; g<4; g++){
    int nt = g*4 + wv;
    #pragma unroll
    for (int kt=0; kt<2; kt++)
      Bf[g][kt] = *(const bf16x8*)(Bb + (size_t)(nt*16+m)*64 + kt*32 + q*8);
  }
  float bz[4];
  #pragma unroll
  for (int g=0; g<4; g++) bz[g] = bi[g*64 + u];

  for (int i = tid; i < (int)(sizeof(Hbuf)/4); i += 256) ((uint32_t*)Hbuf)[i] = 0u;

  const ushort_t* xzr = xz1R + ((size_t)dir*BB + (size_t)(cb*4+q))*TT*256 + (size_t)u*4;
  uint2 pz[4];
  #pragma unroll
  for (int j=0; j<4; j++){
    int tj = dir ? (TT-1-j) : j;
    pz[j] = *(const uint2*)(xzr + (size_t)tj*256);
  }
  __syncthreads();

  const floatx4 z4 = {0.f,0.f,0.f,0.f};
  float cst = 0.f, hl = 0.f;
  const int mb = m & ~3;                   // broadcast source row

  for (int i = 0; i < TT/4; ++i){
    #pragma unroll
    for (int p = 0; p < 4; ++p){
      const int s = i*4 + p;
      const int cur = s & 1, nxt = cur ^ 1;

      bf16x8 Af[2];
      const ushort_t* ar = &Hbuf[cur][mb][0];
      Af[0] = *(const bf16x8*)(ar + q*8);
      Af[1] = *(const bf16x8*)(ar + 32 + q*8);

      floatx4 a0 = __builtin_amdgcn_mfma_f32_16x16x32_bf16(Af[0], Bf[0][0], z4, 0,0,0);
      floatx4 a1 = __builtin_amdgcn_mfma_f32_16x16x32_bf16(Af[0], Bf[1][0], z4, 0,0,0);
      floatx4 a2 = __builtin_amdgcn_mfma_f32_16x16x32_bf16(Af[0], Bf[2][0], z4, 0,0,0);
      floatx4 a3 = __builtin_amdgcn_mfma_f32_16x16x32_bf16(Af[0], Bf[3][0], z4, 0,0,0);
      a0 = __builtin_amdgcn_mfma_f32_16x16x32_bf16(Af[1], Bf[0][1], a0, 0,0,0);
      a1 = __builtin_amdgcn_mfma_f32_16x16x32_bf16(Af[1], Bf[1][1], a1, 0,0,0);
      a2 = __builtin_amdgcn_mfma_f32_16x16x32_bf16(Af[1], Bf[2][1], a2, 0,0,0);
      a3 = __builtin_amdgcn_mfma_f32_16x16x32_bf16(Af[1], Bf[3][1], a3, 0,0,0);

      // consume pz[p] (loaded 4 steps ago), then reload for step s+4
      float z0 = a0[0] + bz[0] + bf2f((ushort_t)(pz[p].x & 0xffff));
      float z1 = a1[0] + bz[1] + bf2f((ushort_t)(pz[p].x >> 16));
      float z2 = a2[0] + bz[2] + bf2f((ushort_t)(pz[p].y & 0xffff));
      float z3 = a3[0] + bz[3] + bf2f((ushort_t)(pz[p].y >> 16));
      {
        int sn = s + 4; if (sn > TT-1) sn = TT-1;
        int tn = dir ? (TT-1-sn) : sn;
        pz[p] = *(const uint2*)(xzr + (size_t)tn*256);
      }

      {
        float ig = fsig(z0), fg = fsig(z1), og = fsig(z3);
        float gg = ftanh(z2);
        float cc = fg*cst + ig*gg;
        cst = cc;
        hl = og*ftanh(cc);
        Hbuf[nxt][q*4][u] = f2bf(hl);
      }
      ldsbar();
    }
  }
  h1last[(size_t)(cb*4 + q)*128 + dir*64 + u] = hl;
}

// ---------------- K4: dense head
__global__ __launch_bounds__(128) void k_head(
  const float* __restrict__ h1last,
  const float* __restrict__ d0W, const float* __restrict__ d0b,
  const float* __restrict__ d1W, const float* __restrict__ d1b,
  const float* __restrict__ oW,  const float* __restrict__ ob,
  float* __restrict__ outp)
{
  const int b = blockIdx.x;
  const int j = threadIdx.x;
  __shared__ float v0[128], v1[128];
  v0[j] = h1last[b*128 + j];
  __syncthreads();
  float acc = d0b[j];
  #pragma unroll
  for (int k=0;k<128;k++) acc += v0[k]*d0W[k*128 + j];
  v1[j] = fmaxf(acc, 0.f);
  __syncthreads();
  if (j < 64){
    float a2 = d1b[j];
    #pragma unroll
    for (int k=0;k<128;k++) a2 += v1[k]*d1W[k*64 + j];
    float p = fmaxf(a2, 0.f) * oW[j];
    #pragma unroll
    for (int off=32; off>0; off>>=1) p += __shfl_down(p, off, 64);
    if (j == 0) outp[b] = 1.f/(1.f + __expf(-(p + ob[0])));
  }
}

extern "C" void kernel_launch(void* const* d_in, const int* in_sizes, int n_in,
                              void* d_out, int out_size, void* d_ws, size_t ws_size,
                              hipStream_t stream)
{
  const float* x     = (const float*)d_in[0];
  const float* l0fWx = (const float*)d_in[1];
  const float* l0fWh = (const float*)d_in[2];
  const float* l0fb  = (const float*)d_in[3];
  const float* l0bWx = (const float*)d_in[4];
  const float* l0bWh = (const float*)d_in[5];
  const float* l0bb  = (const float*)d_in[6];
  const float* l1fWx = (const float*)d_in[7];
  const float* l1fWh = (const float*)d_in[8];
  const float* l1fb  = (const float*)d_in[9];
  const float* l1bWx = (const float*)d_in[10];
  const float* l1bWh = (const float*)d_in[11];
  const float* l1bb  = (const float*)d_in[12];
  const float* d0W = (const float*)d_in[13];
  const float* d0b = (const float*)d_in[14];
  const float* d1W = (const float*)d_in[15];
  const float* d1b = (const float*)d_in[16];
  const float* oW  = (const float*)d_in[17];
  const float* ob  = (const float*)d_in[18];
  float* outp = (float*)d_out;

  char* ws = (char*)d_ws;
  // Workspace: total 260,210,688 B (r1-r7-proven budget).
  // xA (10,485,760 B) overlaps the head of the xz1 region — lifetimes disjoint
  // (xA read only by k_lstm0m; xz1 written by k_xz1_gemm afterwards).
  const size_t OFF_XT  = 0;                        // xc: 7,208,960 (slot 7,864,320)
  const size_t OFF_H0  = OFF_XT  + 7864320ull;     // 83,886,080
  const size_t OFF_XZ  = OFF_H0  + 83886080ull;    // 167,772,160 (xz1R; xA overlaps head)
  const size_t OFF_XA  = OFF_XZ;                   // xA: 10,485,760 (dead before xz1 written)
  const size_t OFF_WT  = OFF_XZ  + 167772160ull;   // 262,144
  const size_t OFF_B0  = OFF_WT  + 262144ull;      // 327,680
  const size_t OFF_B1  = OFF_B0  + 327680ull;      // 65,536
  const size_t OFF_H1  = OFF_B1  + 65536ull;       // 32,768

  ushort_t* xc  = (ushort_t*)(ws + OFF_XT);
  ushort_t* h0  = (ushort_t*)(ws + OFF_H0);
  ushort_t* xz1 = (ushort_t*)(ws + OFF_XZ);
  ushort_t* xA  = (ushort_t*)(ws + OFF_XA);
  ushort_t* WT  = (ushort_t*)(ws + OFF_WT);
  ushort_t* B0T = (ushort_t*)(ws + OFF_B0);
  ushort_t* B1T = (ushort_t*)(ws + OFF_B1);
  float*    h1l = (float*)(ws + OFF_H1);

  hipLaunchKernelGGL(k_convert_x,   dim3(3520), dim3(256), 0, stream, x, xc);
  hipLaunchKernelGGL(k_prep_xa,     dim3(2560), dim3(256), 0, stream, xc, xA);
  hipLaunchKernelGGL(k_prep_l0,     dim3(640),  dim3(256), 0, stream, l0fWx, l0fWh, l0bWx, l0bWh, B0T);
  hipLaunchKernelGGL(k_prep_l1,     dim3(128),  dim3(256), 0, stream, l1fWh, l1bWh, B1T);
  hipLaunchKernelGGL(k_prep_wxT,    dim3(512),  dim3(256), 0, stream, l1fWx, l1bWx, WT);
  hipLaunchKernelGGL(k_lstm0m,      dim3(32),   dim3(512), 0, stream, xA, B0T, l0fb, l0bb, h0);
  hipLaunchKernelGGL(k_xz1_gemm,    dim3(1280,2), dim3(512), 0, stream, h0, WT, xz1);
  hipLaunchKernelGGL(k_lstm1m,      dim3(32),   dim3(256), 0, stream, xz1, B1T, l1fb, l1bb, h1l);
  hipLaunchKernelGGL(k_head,        dim3(64),   dim3(128), 0, stream,
                     h1l, d0W, d0b, d1W, d1b, oW, ob, outp);
}